// Round 10
// baseline (131.862 us; speedup 1.0000x reference)
//
#include <hip/hip_runtime.h>
#include <hip/hip_bf16.h>

#define S_   8
#define N_   1024
#define KG_  16
#define MW_  64
#define CI_  128
#define CO_  256

typedef __attribute__((ext_vector_type(8))) short bf16x8;
typedef __attribute__((ext_vector_type(4))) float f32x4;

// ---------------------------------------------------------------------------
// Fused: W fp32->bf16 convert + circular sliding-window sums (bf16 out).
// win2[s][t][c] = win2[s][t+1024][c] = sum_{m<64} x[s][(t+m)%N][c]
// Output DUPLICATED across 2N rows so the GEMM needs no circular wrap.
// ---------------------------------------------------------------------------
__global__ __launch_bounds__(256) void win_kernel(const float* __restrict__ x,
                                                  const float* __restrict__ W,
                                                  __hip_bfloat16* __restrict__ win,
                                                  __hip_bfloat16* __restrict__ Wb) {
    __shared__ float lds[96][CI_];           // 48 KB
    const int b   = blockIdx.x;              // 0..255
    const int tid = threadIdx.x;

    // --- W conversion: 8 elems per thread ---
    {
        const int wi = (b * 256 + tid) * 8;
        const float4 v0 = *(const float4*)&W[wi];
        const float4 v1 = *(const float4*)&W[wi + 4];
        union { unsigned short u[8]; uint4 v; } o;
        __hip_bfloat16 h;
        h = __float2bfloat16(v0.x); o.u[0] = *(unsigned short*)&h;
        h = __float2bfloat16(v0.y); o.u[1] = *(unsigned short*)&h;
        h = __float2bfloat16(v0.z); o.u[2] = *(unsigned short*)&h;
        h = __float2bfloat16(v0.w); o.u[3] = *(unsigned short*)&h;
        h = __float2bfloat16(v1.x); o.u[4] = *(unsigned short*)&h;
        h = __float2bfloat16(v1.y); o.u[5] = *(unsigned short*)&h;
        h = __float2bfloat16(v1.z); o.u[6] = *(unsigned short*)&h;
        h = __float2bfloat16(v1.w); o.u[7] = *(unsigned short*)&h;
        *(uint4*)&Wb[wi] = o.v;
    }

    // --- sliding window ---
    const int s   = b >> 5;
    const int t0  = (b & 31) << 5;           // 32 t's per block
    const float* xs = x + (size_t)s * N_ * CI_;

    for (int e = tid * 4; e < 96 * CI_; e += 256 * 4) {
        const int r = e >> 7;
        const int c = e & (CI_ - 1);
        *(float4*)&lds[r][c] = *(const float4*)&xs[((t0 + r) & (N_ - 1)) * CI_ + c];
    }
    __syncthreads();

    const int c  = tid & (CI_ - 1);
    const int tb = (tid >> 7) << 4;          // 0 or 16
    float s0 = 0.f, s1 = 0.f, s2 = 0.f, s3 = 0.f;
    #pragma unroll
    for (int m = 0; m < MW_; m += 4) {
        s0 += lds[tb + m + 0][c];
        s1 += lds[tb + m + 1][c];
        s2 += lds[tb + m + 2][c];
        s3 += lds[tb + m + 3][c];
    }
    float w = (s0 + s1) + (s2 + s3);
    __hip_bfloat16* wo = win + (size_t)s * (2 * N_) * CI_;
    {
        const int row = t0 + tb;
        const __hip_bfloat16 hv = __float2bfloat16(w);
        wo[row * CI_ + c] = hv;
        wo[(row + N_) * CI_ + c] = hv;
    }
    #pragma unroll
    for (int t = 1; t < 16; ++t) {
        w += lds[tb + t - 1 + MW_][c] - lds[tb + t - 1][c];
        const int row = t0 + tb + t;
        const __hip_bfloat16 hv = __float2bfloat16(w);
        wo[row * CI_ + c] = hv;
        wo[(row + N_) * CI_ + c] = hv;
    }
}

// ---------------------------------------------------------------------------
// out[s,n,o] = sum_{g,c} win2[s,n+64g,c] * W[g,o,c]
// LDS MFMA GEMM, HIGH OCCUPANCY + SELF-PROFILING (REPEAT=4).
// BM=64, BN=32, BK=64 -> LDS (8KB A + 4KB B) x2 dbuf = 24 KB => 4 blocks/CU,
// 16 waves/CU (2x all prior rounds). Grid 1024 = 8 XCD-pinned s x 128 tiles.
// 4 waves; wave tile 16x32 (1x2 frags 16x16x32 bf16, 2 ksub). 3 staging
// loads/wave/step, counted vmcnt(3). REPEAT=4: whole GEMM repeated
// idempotently inside one dispatch so it exceeds the ~41us fill cutoff and
// surfaces full rocprof counters (rates are per-rep representative).
// ---------------------------------------------------------------------------
#define BKE  64                 // K elems per step
#define AST  (64 * BKE)         // 8 KB
#define BST  (32 * BKE)         // 4 KB
#define KSTEPS 32
#define REPEAT 4

__global__ __launch_bounds__(256, 4) void gemm_kernel(const __hip_bfloat16* __restrict__ winb,
                                                      const __hip_bfloat16* __restrict__ Wb,
                                                      float* __restrict__ out) {
    __shared__ __align__(16) unsigned short Alds[2 * AST];   // 16 KB
    __shared__ __align__(16) unsigned short Blds[2 * BST];   //  8 KB

    const int tid = threadIdx.x;
    const int l   = tid & 63;
    const int wv  = tid >> 6;                // 0..3
    const int s   = blockIdx.x & 7;          // XCD-pinned sample index
    const int rem = blockIdx.x >> 3;         // 0..127
    const int n0  = (rem & 15) << 6;         // 64-row tile
    const int o0  = (rem >> 4) << 5;         // 32-col tile (8 o-tiles)

    const int fr = l & 15;
    const int kq = l >> 4;                   // 0..3
    const int rl = l >> 3;                   // staging: row within 8-row chunk
    const int ps = l & 7;                    // staging: physical 16B slot

    // win2 has 2N rows: no circular mask needed (max row 960+960+63 < 2048)
    const unsigned short* winp = (const unsigned short*)winb
                               + ((size_t)s * 2 * N_ + n0) * CI_;
    const unsigned short* Wp   = (const unsigned short*)Wb;

    // stage tile t into buffer: A 8 chunks of 1KB, B 4 chunks; 3 per wave
    auto stage = [&](int t, unsigned short* Ab, unsigned short* Bb) {
        const int g  = t >> 1;
        const int ch = (t & 1) << 6;         // K half within the group
        #pragma unroll
        for (int q = 0; q < 2; ++q) {
            const int rb  = (wv * 2 + q) * 8;
            const int row = rb + rl;
            const int ss  = ps ^ (row & 7);
            const unsigned short* src = winp + (g * MW_ + row) * CI_ + ch + ss * 8;
            __builtin_amdgcn_global_load_lds((const __attribute__((address_space(1))) void*)src,
                                             (__attribute__((address_space(3))) void*)(Ab + rb * BKE),
                                             16, 0, 0);
        }
        {
            const int rb  = wv * 8;
            const int row = rb + rl;         // o index within tile (0..31)
            const int ss  = ps ^ (row & 7);
            const unsigned short* src = Wp + ((g * CO_ + o0 + row) * CI_) + ch + ss * 8;
            __builtin_amdgcn_global_load_lds((const __attribute__((address_space(1))) void*)src,
                                             (__attribute__((address_space(3))) void*)(Bb + rb * BKE),
                                             16, 0, 0);
        }
    };

    for (int rep = 0; rep < REPEAT; ++rep) {
        f32x4 acc0 = {0.f, 0.f, 0.f, 0.f};
        f32x4 acc1 = {0.f, 0.f, 0.f, 0.f};

        stage(0, Alds, Blds);                // 3 loads in flight

        for (int t = 0; t < KSTEPS; ++t) {
            const int cur = t & 1;
            if (t < KSTEPS - 1) {
                stage(t + 1, Alds + (cur ^ 1) * AST, Blds + (cur ^ 1) * BST);
                asm volatile("s_waitcnt vmcnt(3)" ::: "memory");   // tile t done
            } else {
                asm volatile("s_waitcnt vmcnt(0)" ::: "memory");
            }
            __builtin_amdgcn_sched_barrier(0);
            __builtin_amdgcn_s_barrier();    // buf[cur] ready for all waves

            const unsigned short* Ab = Alds + cur * AST;
            const unsigned short* Bb = Blds + cur * BST;
            #pragma unroll
            for (int ks = 0; ks < 2; ++ks) {
                const int sl = ks * 4 + kq;  // logical 16B slot 0..7
                const int ar = wv * 16 + fr;
                const bf16x8 af = *(const bf16x8*)&Ab[ar * BKE + ((sl ^ (ar & 7)) * 8)];
                const int b0r = fr;
                const int b1r = 16 + fr;
                const bf16x8 bf0 = *(const bf16x8*)&Bb[b0r * BKE + ((sl ^ (b0r & 7)) * 8)];
                const bf16x8 bf1 = *(const bf16x8*)&Bb[b1r * BKE + ((sl ^ (b1r & 7)) * 8)];
                acc0 = __builtin_amdgcn_mfma_f32_16x16x32_bf16(af, bf0, acc0, 0, 0, 0);
                acc1 = __builtin_amdgcn_mfma_f32_16x16x32_bf16(af, bf1, acc1, 0, 0, 0);
            }
            __builtin_amdgcn_sched_barrier(0);
            __builtin_amdgcn_s_barrier();    // all waves done reading buf[cur]
        }

        // D layout: col = lane&15, row = (lane>>4)*4 + reg (validated r2-r9)
        float* op = out + ((size_t)(s * N_ + n0 + wv * 16) * CO_) + o0;
        #pragma unroll
        for (int r = 0; r < 4; ++r) {
            op[(kq * 4 + r) * CO_ + fr]      = acc0[r];
            op[(kq * 4 + r) * CO_ + 16 + fr] = acc1[r];
        }
    }
}

extern "C" void kernel_launch(void* const* d_in, const int* in_sizes, int n_in,
                              void* d_out, int out_size, void* d_ws, size_t ws_size,
                              hipStream_t stream) {
    const float* x = (const float*)d_in[0];   // [S, N, CI]
    const float* W = (const float*)d_in[1];   // [K, CO, CI]

    __hip_bfloat16* winb = (__hip_bfloat16*)d_ws;                               // 4 MB (2N rows)
    __hip_bfloat16* Wbb  = (__hip_bfloat16*)((char*)d_ws +
                              (size_t)S_ * 2 * N_ * CI_ * sizeof(__hip_bfloat16)); // 1 MB
    float* out = (float*)d_out;               // [S, N, CO] fp32

    win_kernel<<<256, 256, 0, stream>>>(x, W, winb, Wbb);
    gemm_kernel<<<1024, 256, 0, stream>>>(winb, Wbb, out);
}

// Round 11
// 82.058 us; speedup vs baseline: 1.6069x; 1.6069x over previous
//
#include <hip/hip_runtime.h>
#include <hip/hip_bf16.h>

#define S_   8
#define N_   1024
#define KG_  16
#define MW_  64
#define CI_  128
#define CO_  256

typedef __attribute__((ext_vector_type(8))) short bf16x8;
typedef __attribute__((ext_vector_type(4))) float f32x4;

// ---------------------------------------------------------------------------
// Fused: W fp32->bf16 convert + circular sliding-window sums (bf16 out).
// win2[s][t][c] = win2[s][t+1024][c] = sum_{m<64} x[s][(t+m)%N][c]
// Output DUPLICATED across 2N rows so the GEMM needs no circular wrap.
// ---------------------------------------------------------------------------
__global__ __launch_bounds__(256) void win_kernel(const float* __restrict__ x,
                                                  const float* __restrict__ W,
                                                  __hip_bfloat16* __restrict__ win,
                                                  __hip_bfloat16* __restrict__ Wb) {
    __shared__ float lds[96][CI_];           // 48 KB
    const int b   = blockIdx.x;              // 0..255
    const int tid = threadIdx.x;

    // --- W conversion: 8 elems per thread ---
    {
        const int wi = (b * 256 + tid) * 8;
        const float4 v0 = *(const float4*)&W[wi];
        const float4 v1 = *(const float4*)&W[wi + 4];
        union { unsigned short u[8]; uint4 v; } o;
        __hip_bfloat16 h;
        h = __float2bfloat16(v0.x); o.u[0] = *(unsigned short*)&h;
        h = __float2bfloat16(v0.y); o.u[1] = *(unsigned short*)&h;
        h = __float2bfloat16(v0.z); o.u[2] = *(unsigned short*)&h;
        h = __float2bfloat16(v0.w); o.u[3] = *(unsigned short*)&h;
        h = __float2bfloat16(v1.x); o.u[4] = *(unsigned short*)&h;
        h = __float2bfloat16(v1.y); o.u[5] = *(unsigned short*)&h;
        h = __float2bfloat16(v1.z); o.u[6] = *(unsigned short*)&h;
        h = __float2bfloat16(v1.w); o.u[7] = *(unsigned short*)&h;
        *(uint4*)&Wb[wi] = o.v;
    }

    // --- sliding window ---
    const int s   = b >> 5;
    const int t0  = (b & 31) << 5;           // 32 t's per block
    const float* xs = x + (size_t)s * N_ * CI_;

    for (int e = tid * 4; e < 96 * CI_; e += 256 * 4) {
        const int r = e >> 7;
        const int c = e & (CI_ - 1);
        *(float4*)&lds[r][c] = *(const float4*)&xs[((t0 + r) & (N_ - 1)) * CI_ + c];
    }
    __syncthreads();

    const int c  = tid & (CI_ - 1);
    const int tb = (tid >> 7) << 4;          // 0 or 16
    float s0 = 0.f, s1 = 0.f, s2 = 0.f, s3 = 0.f;
    #pragma unroll
    for (int m = 0; m < MW_; m += 4) {
        s0 += lds[tb + m + 0][c];
        s1 += lds[tb + m + 1][c];
        s2 += lds[tb + m + 2][c];
        s3 += lds[tb + m + 3][c];
    }
    float w = (s0 + s1) + (s2 + s3);
    __hip_bfloat16* wo = win + (size_t)s * (2 * N_) * CI_;
    {
        const int row = t0 + tb;
        const __hip_bfloat16 hv = __float2bfloat16(w);
        wo[row * CI_ + c] = hv;
        wo[(row + N_) * CI_ + c] = hv;
    }
    #pragma unroll
    for (int t = 1; t < 16; ++t) {
        w += lds[tb + t - 1 + MW_][c] - lds[tb + t - 1][c];
        const int row = t0 + tb + t;
        const __hip_bfloat16 hv = __float2bfloat16(w);
        wo[row * CI_ + c] = hv;
        wo[(row + N_) * CI_ + c] = hv;
    }
}

// ---------------------------------------------------------------------------
// out[s,n,o] = sum_{g,c} win2[s,n+64g,c] * W[g,o,c]
// LDS MFMA GEMM, read-efficiency + occupancy balanced (r10 PMC-driven):
// r10 was at its LDS-read-issue wall (6 ds_read per 4 MFMA, 786k reads
// ~15.4us). New: BM=64, BN=64, 4 waves = 2 col-halves (pw) x 2 K-pipes
// (pipe), wave tile 64x32 -> 6 ds_read per 8 MFMA (reads halved; LDS-issue
// wall ~7.7us; L2 staged traffic 262MB ~7.6us; walls balanced).
// BK=64/pipe, 16 steps. LDS 64 KB dbuf, 2 blocks/CU (grid 512, XCD-pinned),
// 8 waves/CU. Both waves of a pipe read the pipe's full staged A+B (dedup).
// r10 skeleton: gload_lds + involution swizzle + counted vmcnt(8) +
// 2 barriers/step. Pipe partials reduced via LDS (reused) + 1 barrier.
// ---------------------------------------------------------------------------
#define KSTEPS 16

__global__ __launch_bounds__(256, 2) void gemm_kernel(const __hip_bfloat16* __restrict__ winb,
                                                      const __hip_bfloat16* __restrict__ Wb,
                                                      float* __restrict__ out) {
    // 64 KB: A region [pipe][buf][64][64] = 32 KB, B region same = 32 KB.
    __shared__ __align__(16) unsigned short smem[32768];

    const int tid  = threadIdx.x;
    const int l    = tid & 63;
    const int wv   = tid >> 6;               // 0..3
    const int pw   = wv & 1;                 // col half (0: cols 0-31, 1: 32-63)
    const int pipe = wv >> 1;                // K half (0: g 0-7, 1: g 8-15)
    const int s    = blockIdx.x & 7;         // XCD-pinned sample index
    const int rem  = blockIdx.x >> 3;        // 0..63
    const int n0   = (rem & 15) << 6;        // 64-row tile
    const int o0   = (rem >> 4) << 6;        // 64-col tile

    const int fr = l & 15;
    const int kq = l >> 4;                   // 0..3
    const int rl = l >> 3;                   // staging: row within 8-row chunk
    const int ps = l & 7;                    // staging: physical 16B slot

    const unsigned short* winp = (const unsigned short*)winb
                               + ((size_t)s * 2 * N_ + n0) * CI_;
    const unsigned short* Wp   = (const unsigned short*)Wb;

#define AELEM(P, B) (smem + ((P) * 2 + (B)) * 4096)
#define BELEM(P, B) (smem + 16384 + ((P) * 2 + (B)) * 4096)

    f32x4 acc[4][2];
    #pragma unroll
    for (int i = 0; i < 4; ++i)
        #pragma unroll
        for (int j = 0; j < 2; ++j)
            acc[i][j] = f32x4{0.f, 0.f, 0.f, 0.f};

    // Stage step t of this wave's pipe into buffer buf.
    // Per pipe: A 8 chunks + B 8 chunks; each wave (pw) does 4+4.
    auto stage = [&](int t, int buf) {
        const int g  = pipe * 8 + (t >> 1);
        const int ch = (t & 1) << 6;         // K half within the group
        unsigned short* Ab = AELEM(pipe, buf);
        unsigned short* Bb = BELEM(pipe, buf);
        #pragma unroll
        for (int q = 0; q < 4; ++q) {
            const int row = (pw * 4 + q) * 8 + rl;     // 0..63
            const int ss  = ps ^ (row & 7);
            const unsigned short* src = winp + (g * MW_ + row) * CI_ + ch + ss * 8;
            __builtin_amdgcn_global_load_lds((const __attribute__((address_space(1))) void*)src,
                                             (__attribute__((address_space(3))) void*)(Ab + ((pw * 4 + q) * 8) * 64),
                                             16, 0, 0);
        }
        #pragma unroll
        for (int q = 0; q < 4; ++q) {
            const int row = (pw * 4 + q) * 8 + rl;     // o index 0..63
            const int ss  = ps ^ (row & 7);
            const unsigned short* src = Wp + ((g * CO_ + o0 + row) * CI_) + ch + ss * 8;
            __builtin_amdgcn_global_load_lds((const __attribute__((address_space(1))) void*)src,
                                             (__attribute__((address_space(3))) void*)(Bb + ((pw * 4 + q) * 8) * 64),
                                             16, 0, 0);
        }
    };

    stage(0, 0);                             // 8 loads in flight

    for (int t = 0; t < KSTEPS; ++t) {
        const int cur = t & 1;
        if (t < KSTEPS - 1) {
            stage(t + 1, cur ^ 1);           // +8 -> 16 in flight
            asm volatile("s_waitcnt vmcnt(8)" ::: "memory");   // tile t done
        } else {
            asm volatile("s_waitcnt vmcnt(0)" ::: "memory");
        }
        __builtin_amdgcn_sched_barrier(0);
        __builtin_amdgcn_s_barrier();        // buf[cur] ready for all waves

        const unsigned short* Ab = AELEM(pipe, cur);
        const unsigned short* Bb = BELEM(pipe, cur);
        #pragma unroll
        for (int ks = 0; ks < 2; ++ks) {
            const int sl = ks * 4 + kq;      // logical 16B slot 0..7
            bf16x8 af[4], bfg[2];
            #pragma unroll
            for (int i = 0; i < 4; ++i) {
                const int ar = i * 16 + fr;
                af[i] = *(const bf16x8*)&Ab[ar * 64 + ((sl ^ (ar & 7)) * 8)];
            }
            #pragma unroll
            for (int j = 0; j < 2; ++j) {
                const int br = pw * 32 + j * 16 + fr;
                bfg[j] = *(const bf16x8*)&Bb[br * 64 + ((sl ^ (br & 7)) * 8)];
            }
            #pragma unroll
            for (int i = 0; i < 4; ++i)
                #pragma unroll
                for (int j = 0; j < 2; ++j)
                    acc[i][j] = __builtin_amdgcn_mfma_f32_16x16x32_bf16(af[i], bfg[j], acc[i][j], 0, 0, 0);
        }
        __builtin_amdgcn_sched_barrier(0);
        __builtin_amdgcn_s_barrier();        // all waves done reading buf[cur]
    }

    // Reduce the 2 K-pipes via LDS (reuse smem; last barrier above protects).
    // D layout: col = lane&15, row = (lane>>4)*4 + reg (validated r2-r10).
    float* red = (float*)smem;               // [2][64][68] = 34.8 KB
    #pragma unroll
    for (int i = 0; i < 4; ++i)
        #pragma unroll
        for (int j = 0; j < 2; ++j)
            #pragma unroll
            for (int r = 0; r < 4; ++r)
                red[((pipe * 64) + (i * 16 + kq * 4 + r)) * 68 + pw * 32 + j * 16 + fr]
                    = acc[i][j][r];

    __syncthreads();

    const int row = tid >> 2;                // 0..63
    const int cb  = (tid & 3) << 4;          // 0,16,32,48
    float* op = out + ((size_t)(s * N_ + n0 + row) * CO_) + o0 + cb;
    #pragma unroll
    for (int q = 0; q < 4; ++q) {
        const f32x4 v0 = *(const f32x4*)&red[(row) * 68 + cb + q * 4];
        const f32x4 v1 = *(const f32x4*)&red[(64 + row) * 68 + cb + q * 4];
        *(f32x4*)&op[q * 4] = v0 + v1;
    }
}

extern "C" void kernel_launch(void* const* d_in, const int* in_sizes, int n_in,
                              void* d_out, int out_size, void* d_ws, size_t ws_size,
                              hipStream_t stream) {
    const float* x = (const float*)d_in[0];   // [S, N, CI]
    const float* W = (const float*)d_in[1];   // [K, CO, CI]

    __hip_bfloat16* winb = (__hip_bfloat16*)d_ws;                               // 4 MB (2N rows)
    __hip_bfloat16* Wbb  = (__hip_bfloat16*)((char*)d_ws +
                              (size_t)S_ * 2 * N_ * CI_ * sizeof(__hip_bfloat16)); // 1 MB
    float* out = (float*)d_out;               // [S, N, CO] fp32

    win_kernel<<<256, 256, 0, stream>>>(x, W, winb, Wbb);
    gemm_kernel<<<512, 256, 0, stream>>>(winb, Wbb, out);
}